// Round 22
// baseline (1541.647 us; speedup 1.0000x reference)
//
#include <hip/hip_runtime.h>

#define BATCH   16
#define NPTS    4096
#define NPOINT  1024
#define NSAMPLE 32
#define NCB     7           // consumer blocks per batch (16 + 16*7 = 128 blocks)
#define PUBK    16          // producer publishes progress every PUBK iters

typedef float v2f __attribute__((ext_vector_type(2)));
typedef float v4f __attribute__((ext_vector_type(4)));
typedef const __attribute__((address_space(4))) float cs_float;
typedef const __attribute__((address_space(4))) v4f   cs_v4f;
typedef unsigned long long ull;

// ---------------------------------------------------------------------------
// Kernel P: one-block prep — fold BN scale into TRANSPOSED weight copies in
// d_ws. Layout at ws+2MB: Wt1[64][8] | Wt2[64][64] | Wt3[128][64] | biases.
// ---------------------------------------------------------------------------
__global__ __launch_bounds__(256)
void prep_kernel(const float* __restrict__ W1, const float* __restrict__ g1,
                 const float* __restrict__ b1, const float* __restrict__ m1,
                 const float* __restrict__ v1,
                 const float* __restrict__ W2, const float* __restrict__ g2,
                 const float* __restrict__ b2, const float* __restrict__ m2,
                 const float* __restrict__ v2,
                 const float* __restrict__ W3, const float* __restrict__ g3,
                 const float* __restrict__ b3, const float* __restrict__ m3,
                 const float* __restrict__ v3,
                 float* __restrict__ wt)
{
    const int t = threadIdx.x;
    float* Wt1 = wt;                    // 512
    float* Wt2 = wt + 512;              // 4096
    float* Wt3 = wt + 512 + 4096;       // 8192
    float* bi1 = wt + 512 + 4096 + 8192;
    float* bi2 = bi1 + 64;
    float* bi3 = bi2 + 64;

    for (int e = t; e < 64 * 8; e += 256) {
        int d = e >> 3, c = e & 7;
        float sc = g1[d] / sqrtf(v1[d] + 1e-5f);
        Wt1[e] = (c < 6) ? W1[c * 64 + d] * sc : 0.f;
    }
    for (int e = t; e < 64 * 64; e += 256) {
        int d = e >> 6, c = e & 63;
        float sc = g2[d] / sqrtf(v2[d] + 1e-5f);
        Wt2[e] = W2[c * 64 + d] * sc;
    }
    for (int e = t; e < 128 * 64; e += 256) {
        int d = e >> 6, c = e & 63;
        float sc = g3[d] / sqrtf(v3[d] + 1e-5f);
        Wt3[e] = W3[c * 128 + d] * sc;
    }
    for (int d = t; d < 64; d += 256) {
        float s1v = g1[d] / sqrtf(v1[d] + 1e-5f);
        bi1[d] = b1[d] - m1[d] * s1v;
        float s2v = g2[d] / sqrtf(v2[d] + 1e-5f);
        bi2[d] = b2[d] - m2[d] * s2v;
    }
    for (int d = t; d < 128; d += 256) {
        float s3v = g3[d] / sqrtf(v3[d] + 1e-5f);
        bi3[d] = b3[d] - m3[d] * s3v;
    }
}

// ---------------------------------------------------------------------------
// MEGA kernel (ROUND-22): producer-consumer pipeline, half-chip consumers.
// r20/r21 lesson: publication mechanics don't matter — the producer runs
// ~30% slower whenever 240 consumer CUs are co-resident (uniform slowdown =
// boost-clock / fabric co-residency cost, 608*(2400/1850)~=790 matches).
// Test: NCB 15->7 (128 blocks total, half the chip idle; consumers keep 7x
// throughput headroom) + deficit-adaptive s_sleep backoff (poll traffic and
// spin power down ~50x).
// ---------------------------------------------------------------------------
__global__ __attribute__((amdgpu_waves_per_eu(1, 1))) __launch_bounds__(256)
void mega_kernel(const float* __restrict__ xyz, const float* __restrict__ points,
                 const float* __restrict__ wt, int* __restrict__ prog,
                 float* __restrict__ cent,
                 float* __restrict__ new_xyz, float* __restrict__ feat)
{
    __shared__ __align__(16) float s4[NPTS * 4];            // producer cloud
    __shared__ __align__(16) unsigned long long sC[2][4];   // fps candidates
    __shared__ int sIdxBuf[4][64];                          // consumer idx handoff

    const int t    = threadIdx.x;
    const int lane = t & 63;
    const int wv   = t >> 6;

    if (blockIdx.x < BATCH) {
        // ================= FPS producer (validated r17 core) =============
#pragma clang fp contract(off)
        const int b = blockIdx.x;
        const float* xb = xyz + (size_t)b * NPTS * 3;
        float* cb = cent + (size_t)b * NPOINT * 4;
        int* pb = prog + b * 32;                            // padded line

        v2f px2[8], py2[8], pz2[8], dist2[8];
#pragma unroll
        for (int j = 0; j < 16; ++j) {
            const int n = j * 256 + t;
            float X = xb[n * 3 + 0];
            float Y = xb[n * 3 + 1];
            float Z = xb[n * 3 + 2];
            s4[n * 4 + 0] = X; s4[n * 4 + 1] = Y; s4[n * 4 + 2] = Z;
            asm volatile("" : "+v"(X), "+v"(Y), "+v"(Z));
            const int p = j >> 1;
            if (j & 1) { px2[p].y = X; py2[p].y = Y; pz2[p].y = Z; dist2[p].y = 1e10f; }
            else       { px2[p].x = X; py2[p].x = Y; pz2[p].x = Z; dist2[p].x = 1e10f; }
        }
        __syncthreads();

        float cx = s4[0], cy = s4[1], cz = s4[2];
        float* out = new_xyz + (size_t)b * NPOINT * 3;

        for (int i = 0; i < NPOINT; ++i) {
            if (t == 0) {            // wave 0: pure output (standalone profile)
                out[i*3+0] = cx; out[i*3+1] = cy; out[i*3+2] = cz;
            }
            if (t == 64) {           // wave 1: mailbox (LLC-direct sc1 stores)
                ull xy = ((ull)__float_as_uint(cy) << 32) |
                         (ull)__float_as_uint(cx);
                __hip_atomic_store((ull*)&cb[i*4], xy, __ATOMIC_RELAXED,
                                   __HIP_MEMORY_SCOPE_AGENT);
                __hip_atomic_store(&cb[i*4+2], cz, __ATOMIC_RELAXED,
                                   __HIP_MEMORY_SCOPE_AGENT);
            }

            v2f c2x; c2x.x = cx; c2x.y = cx;
            v2f c2y; c2y.x = cy; c2y.y = cy;
            v2f c2z; c2z.x = cz; c2z.y = cz;
#pragma unroll
            for (int p = 0; p < 8; ++p) {
                v2f dx = px2[p] - c2x;
                v2f dy = py2[p] - c2y;
                v2f dz = pz2[p] - c2z;
                v2f xx = dx * dx;
                v2f yy = dy * dy;
                v2f zz = dz * dz;
                v2f ss = (xx + yy) + zz;
                dist2[p].x = fminf(dist2[p].x, ss.x);
                dist2[p].y = fminf(dist2[p].y, ss.y);
            }

#define D(j) ((j) & 1 ? dist2[(j) >> 1].y : dist2[(j) >> 1].x)
            float mA = fmaxf(fmaxf(D(0),  D(1)),  D(2));
            float mB = fmaxf(fmaxf(D(3),  D(4)),  D(5));
            float mC = fmaxf(fmaxf(D(6),  D(7)),  D(8));
            float mD = fmaxf(fmaxf(D(9),  D(10)), D(11));
            float mE = fmaxf(fmaxf(D(12), D(13)), D(14));
            float mx = fmaxf(fmaxf(fmaxf(mA, mB), mC),
                             fmaxf(fmaxf(mD, mE), D(15)));
            int bj = 15;
#pragma unroll
            for (int j = 15; j >= 0; --j) bj = (D(j) == mx) ? j : bj;
#undef D
            const int bidx = bj * 256 + t;

            unsigned long long cand =
                ((unsigned long long)__float_as_uint(mx) << 32) |
                (unsigned long long)(unsigned int)~bidx;

#define DPP_RED(CTRL, RMASK)                                                   \
            {                                                                  \
                unsigned int oh = (unsigned int)__builtin_amdgcn_update_dpp(   \
                    0, (int)(unsigned int)(cand >> 32), (CTRL), (RMASK), 0xF, true);\
                unsigned int ol = (unsigned int)__builtin_amdgcn_update_dpp(   \
                    0, (int)(unsigned int)cand, (CTRL), (RMASK), 0xF, true);   \
                unsigned long long o =                                         \
                    ((unsigned long long)oh << 32) | (unsigned long long)ol;   \
                if (o > cand) cand = o;                                        \
            }
            DPP_RED(0x121, 0xF)
            DPP_RED(0x122, 0xF)
            DPP_RED(0x124, 0xF)
            DPP_RED(0x128, 0xF)
            DPP_RED(0x142, 0xA)
            DPP_RED(0x143, 0xC)
#undef DPP_RED

            // batched publication on WAVE 1 (orders wave 1's cent stores)
            if (((i & (PUBK - 1)) == (PUBK - 1)) && t == 64) {
                asm volatile("s_waitcnt vmcnt(0)" ::: "memory");
                __hip_atomic_store(pb, i + 1, __ATOMIC_RELAXED,
                                   __HIP_MEMORY_SCOPE_AGENT);
            }

            const int par = i & 1;
            if (lane == 63) sC[par][wv] = cand;
            asm volatile("s_waitcnt lgkmcnt(0)\n\ts_barrier" ::: "memory");

            const ulonglong2* pc = (const ulonglong2*)&sC[par][0];
            ulonglong2 r0 = pc[0], r1 = pc[1];
            const float4* sx4 = (const float4*)s4;
            float4 f0 = sx4[~(unsigned int)r0.x];
            float4 f1 = sx4[~(unsigned int)r0.y];
            float4 f2 = sx4[~(unsigned int)r1.x];
            float4 f3 = sx4[~(unsigned int)r1.y];
            bool s01 = r0.y > r0.x;
            bool s23 = r1.y > r1.x;
            unsigned long long m01 = s01 ? r0.y : r0.x;
            unsigned long long m23 = s23 ? r1.y : r1.x;
            float4 g01; g01.x = s01 ? f1.x : f0.x; g01.y = s01 ? f1.y : f0.y; g01.z = s01 ? f1.z : f0.z;
            float4 g23; g23.x = s23 ? f3.x : f2.x; g23.y = s23 ? f3.y : f2.y; g23.z = s23 ? f3.z : f2.z;
            bool sF = m23 > m01;
            cx = sF ? g23.x : g01.x;
            cy = sF ? g23.y : g01.y;
            cz = sF ? g23.z : g01.z;
        }
        return;
    }

    // ================= Consumer role: ball + mlp per query-pair =============
    const int cb_ = blockIdx.x - BATCH;         // 0..111
    const int b   = cb_ / NCB;                  // batch
    const int m   = cb_ % NCB;                  // block-in-batch
    const float* xb = xyz + (size_t)b * NPTS * 3;
    const float* cbm = cent + (size_t)b * NPOINT * 4;
    int* pb = prog + b * 32;

    const cs_v4f*   Wc1 = (const cs_v4f*)(wt);
    const cs_v4f*   Wc2 = (const cs_v4f*)(wt + 512);
    const cs_v4f*   Wc3 = (const cs_v4f*)(wt + 512 + 4096);
    const cs_float* bi1 = (const cs_float*)(wt + 512 + 4096 + 8192);
    const cs_float* bi2 = bi1 + 64;
    const cs_float* bi3 = bi2 + 64;

    const float r2 = (float)(0.2 * 0.2);
    const int NCH  = NPTS / 64;
    const int widx = m * 4 + wv;                // 0..27 wave slot within batch

    for (int p = widx; p < NPOINT / 2; p += NCB * 4) {
        const int i1 = 2 * p, i2 = 2 * p + 1;

        // deficit-adaptive wait: sleep ~3.4us per 8 missing iterations
        int pr;
        while ((pr = __hip_atomic_load(pb, __ATOMIC_RELAXED,
                                       __HIP_MEMORY_SCOPE_AGENT)) < i2 + 1) {
            int naps = ((i2 + 1) - pr) >> 3;
            if (naps > 16) naps = 16;
            if (naps == 0) naps = 1;
            for (int s = 0; s < naps; ++s) __builtin_amdgcn_s_sleep(127);
        }

        float cs0[2], cs1[2], cs2[2];
#pragma unroll
        for (int sub = 0; sub < 2; ++sub) {
            const int qi = sub ? i2 : i1;
            ull xy = __hip_atomic_load((const ull*)&cbm[qi*4], __ATOMIC_RELAXED,
                                       __HIP_MEMORY_SCOPE_AGENT);
            cs0[sub] = __uint_as_float((unsigned int)xy);
            cs1[sub] = __uint_as_float((unsigned int)(xy >> 32));
            cs2[sub] = __hip_atomic_load(&cbm[qi*4+2], __ATOMIC_RELAXED,
                                         __HIP_MEMORY_SCOPE_AGENT);
        }

        // ---- ball x2 (EXACT r17 arithmetic + pipelined global loads) ----
#pragma unroll
        for (int sub = 0; sub < 2; ++sub) {
            const float s0 = cs0[sub], s1 = cs1[sub], s2 = cs2[sub];
            const float ssum = __fadd_rn(__fadd_rn(__fmul_rn(s0,s0), __fmul_rn(s1,s1)),
                                         __fmul_rn(s2,s2));
            int found = 0;
            int first = -1;
            float x = xb[lane*3+0], y = xb[lane*3+1], z = xb[lane*3+2];
            int c = 0;
            while (true) {
                float xn = 0.f, yn = 0.f, zn = 0.f;
                if (c + 1 < NCH) {
                    const float* pp_ = xb + ((size_t)(c + 1) * 64 + lane) * 3;
                    xn = pp_[0]; yn = pp_[1]; zn = pp_[2];
                }
                int n = c * 64 + lane;
                float nsum = __fadd_rn(__fadd_rn(__fmul_rn(x,x), __fmul_rn(y,y)),
                                       __fmul_rn(z,z));
                float dot  = __fmaf_rn(s2, z, __fmaf_rn(s1, y, __fmul_rn(s0, x)));
                float d2   = __fsub_rn(__fadd_rn(ssum, nsum), __fmul_rn(2.0f, dot));
                bool inb = !(d2 > r2);
                unsigned long long mm = __ballot(inb);
                if (first < 0 && mm != 0ull) first = c * 64 + (int)__builtin_ctzll(mm);
                if (inb) {
                    int rank = __popcll(mm & ((1ull << lane) - 1ull));
                    int slot = found + rank;
                    if (slot < NSAMPLE) sIdxBuf[wv][sub * 32 + slot] = n;
                }
                found += __popcll(mm);
                ++c;
                if (c >= NCH || found >= NSAMPLE) break;
                x = xn; y = yn; z = zn;
            }
            if (found > NSAMPLE) found = NSAMPLE;
            for (int slot = found + lane; slot < NSAMPLE; slot += 64)
                sIdxBuf[wv][sub * 32 + slot] = first;
        }
        asm volatile("s_waitcnt lgkmcnt(0)" ::: "memory");

        // ---- mlp: lanes 0-31 -> i1, lanes 32-63 -> i2 (validated r17) ----
        const int sub = lane >> 5;
        const int k   = lane & 31;
        const int qi  = sub ? i2 : i1;
        const int q   = b * NPOINT + qi;
        const int n   = sIdxBuf[wv][lane];
        const float* pp = points + ((size_t)b * NPTS + n) * 3;
        const float* xp = xb + (size_t)n * 3;

        const float in0 = __fsub_rn(xp[0], cs0[sub]);
        const float in1 = __fsub_rn(xp[1], cs1[sub]);
        const float in2 = __fsub_rn(xp[2], cs2[sub]);
        const float in3 = pp[0], in4 = pp[1], in5 = pp[2];

        v2f x2[32];
#pragma unroll
        for (int d = 0; d < 64; ++d) {
            v4f wa = Wc1[d * 2 + 0];
            v4f wb = Wc1[d * 2 + 1];
            float acc = bi1[d];
            acc = fmaf(in0, wa.x, acc);
            acc = fmaf(in1, wa.y, acc);
            acc = fmaf(in2, wa.z, acc);
            acc = fmaf(in3, wa.w, acc);
            acc = fmaf(in4, wb.x, acc);
            acc = fmaf(in5, wb.y, acc);
            float r = fmaxf(acc, 0.f);
            if (d & 1) x2[d >> 1].y = r; else x2[d >> 1].x = r;
        }

        v2f y2[32];
#pragma unroll
        for (int d = 0; d < 64; ++d) {
            v2f a2; a2.x = 0.f; a2.y = 0.f;
#pragma unroll
            for (int cc = 0; cc < 16; ++cc) {
                v4f w = Wc2[d * 16 + cc];
                v2f wlo; wlo.x = w.x; wlo.y = w.y;
                v2f whi; whi.x = w.z; whi.y = w.w;
                a2 += x2[2*cc]     * wlo;
                a2 += x2[2*cc + 1] * whi;
            }
            float r = fmaxf(bi2[d] + (a2.x + a2.y), 0.f);
            if (d & 1) y2[d >> 1].y = r; else y2[d >> 1].x = r;
        }

#define POOL_MAX(vv)                                                           \
        {                                                                      \
            float o_;                                                          \
            o_ = __int_as_float(__builtin_amdgcn_update_dpp(                   \
                0, __float_as_int(vv), 0x121, 0xF, 0xF, true));                \
            vv = fmaxf(vv, o_);                                                \
            o_ = __int_as_float(__builtin_amdgcn_update_dpp(                   \
                0, __float_as_int(vv), 0x122, 0xF, 0xF, true));                \
            vv = fmaxf(vv, o_);                                                \
            o_ = __int_as_float(__builtin_amdgcn_update_dpp(                   \
                0, __float_as_int(vv), 0x124, 0xF, 0xF, true));                \
            vv = fmaxf(vv, o_);                                                \
            o_ = __int_as_float(__builtin_amdgcn_update_dpp(                   \
                0, __float_as_int(vv), 0x128, 0xF, 0xF, true));                \
            vv = fmaxf(vv, o_);                                                \
            vv = fmaxf(vv, __shfl_xor(vv, 16));                                \
        }

        float* fq = feat + (size_t)q * 128;
#pragma unroll
        for (int d = 0; d < 128; ++d) {
            v2f a2; a2.x = 0.f; a2.y = 0.f;
#pragma unroll
            for (int cc = 0; cc < 16; ++cc) {
                v4f w = Wc3[d * 16 + cc];
                v2f wlo; wlo.x = w.x; wlo.y = w.y;
                v2f whi; whi.x = w.z; whi.y = w.w;
                a2 += y2[2*cc]     * wlo;
                a2 += y2[2*cc + 1] * whi;
            }
            float vv = fmaxf(bi3[d] + (a2.x + a2.y), 0.f);
            POOL_MAX(vv)
            if (k == 0) fq[d] = vv;
        }
#undef POOL_MAX
    }
}

extern "C" void kernel_launch(void* const* d_in, const int* in_sizes, int n_in,
                              void* d_out, int out_size, void* d_ws, size_t ws_size,
                              hipStream_t stream)
{
    (void)in_sizes; (void)n_in; (void)out_size; (void)ws_size;

    const float* xyz    = (const float*)d_in[0];
    const float* points = (const float*)d_in[1];
    const float* W1 = (const float*)d_in[2];
    const float* g1 = (const float*)d_in[3];
    const float* b1 = (const float*)d_in[4];
    const float* m1 = (const float*)d_in[5];
    const float* v1 = (const float*)d_in[6];
    const float* W2 = (const float*)d_in[7];
    const float* g2 = (const float*)d_in[8];
    const float* b2 = (const float*)d_in[9];
    const float* m2 = (const float*)d_in[10];
    const float* v2 = (const float*)d_in[11];
    const float* W3 = (const float*)d_in[12];
    const float* g3 = (const float*)d_in[13];
    const float* b3 = (const float*)d_in[14];
    const float* m3 = (const float*)d_in[15];
    const float* v3 = (const float*)d_in[16];

    float* out_f    = (float*)d_out;
    float* new_xyz  = out_f;                                  // B*NPOINT*3
    float* feat     = out_f + (size_t)BATCH * NPOINT * 3;     // B*NPOINT*128

    // ws layout: [0,4KB) prog (128B/batch) | [4KB,260KB) cent | [2MB,..) wt
    int*   prog = (int*)d_ws;
    float* cent = (float*)((char*)d_ws + 4 * 1024);
    float* wt   = (float*)((char*)d_ws + 2 * 1024 * 1024);

    hipMemsetAsync(prog, 0, BATCH * 32 * sizeof(int), stream);
    prep_kernel<<<1, 256, 0, stream>>>(W1, g1, b1, m1, v1,
                                       W2, g2, b2, m2, v2,
                                       W3, g3, b3, m3, v3, wt);
    mega_kernel<<<BATCH + BATCH * NCB, 256, 0, stream>>>(xyz, points, wt, prog,
                                                         cent, new_xyz, feat);
}

// Round 23
// 778.926 us; speedup vs baseline: 1.9792x; 1.9792x over previous
//
#include <hip/hip_runtime.h>

#define BATCH   16
#define NPTS    4096
#define NPOINT  1024
#define NSAMPLE 32
#define NCB     15          // consumer blocks per batch (16 + 16*15 = 256 blocks)
#define PUBK    16          // producer publishes progress every PUBK iters

typedef float v2f __attribute__((ext_vector_type(2)));
typedef float v4f __attribute__((ext_vector_type(4)));
typedef const __attribute__((address_space(4))) float cs_float;
typedef const __attribute__((address_space(4))) v4f   cs_v4f;
typedef unsigned long long ull;

// ---------------------------------------------------------------------------
// Kernel P: one-block prep — fold BN scale into TRANSPOSED weight copies in
// d_ws. Layout at ws+2MB: Wt1[64][8] | Wt2[64][64] | Wt3[128][64] | biases.
// ---------------------------------------------------------------------------
__global__ __launch_bounds__(256)
void prep_kernel(const float* __restrict__ W1, const float* __restrict__ g1,
                 const float* __restrict__ b1, const float* __restrict__ m1,
                 const float* __restrict__ v1,
                 const float* __restrict__ W2, const float* __restrict__ g2,
                 const float* __restrict__ b2, const float* __restrict__ m2,
                 const float* __restrict__ v2,
                 const float* __restrict__ W3, const float* __restrict__ g3,
                 const float* __restrict__ b3, const float* __restrict__ m3,
                 const float* __restrict__ v3,
                 float* __restrict__ wt)
{
    const int t = threadIdx.x;
    float* Wt1 = wt;                    // 512
    float* Wt2 = wt + 512;              // 4096
    float* Wt3 = wt + 512 + 4096;       // 8192
    float* bi1 = wt + 512 + 4096 + 8192;
    float* bi2 = bi1 + 64;
    float* bi3 = bi2 + 64;

    for (int e = t; e < 64 * 8; e += 256) {
        int d = e >> 3, c = e & 7;
        float sc = g1[d] / sqrtf(v1[d] + 1e-5f);
        Wt1[e] = (c < 6) ? W1[c * 64 + d] * sc : 0.f;
    }
    for (int e = t; e < 64 * 64; e += 256) {
        int d = e >> 6, c = e & 63;
        float sc = g2[d] / sqrtf(v2[d] + 1e-5f);
        Wt2[e] = W2[c * 64 + d] * sc;
    }
    for (int e = t; e < 128 * 64; e += 256) {
        int d = e >> 6, c = e & 63;
        float sc = g3[d] / sqrtf(v3[d] + 1e-5f);
        Wt3[e] = W3[c * 128 + d] * sc;
    }
    for (int d = t; d < 64; d += 256) {
        float s1v = g1[d] / sqrtf(v1[d] + 1e-5f);
        bi1[d] = b1[d] - m1[d] * s1v;
        float s2v = g2[d] / sqrtf(v2[d] + 1e-5f);
        bi2[d] = b2[d] - m2[d] * s2v;
    }
    for (int d = t; d < 128; d += 256) {
        float s3v = g3[d] / sqrtf(v3[d] + 1e-5f);
        bi3[d] = b3[d] - m3[d] * s3v;
    }
}

// ---------------------------------------------------------------------------
// MEGA kernel (ROUND-23): producer-consumer pipeline; consumer ball reads
// from LDS SoA. r22 falsified "producer-bound": halving consumers doubled
// duration (VALUBusy 19.8->10.0%), so consumers were the critical path —
// each ball query was a SERIAL global-latency chunk chain (~40us/pair, 10x
// model) because the early-exit makes every L2 round-trip serial and there
// are only 60 waves/batch of TLP. Fix: consumers stage the cloud into LDS
// SoA (sx|sy|sz in the same s4 buffer the producer uses; stride-4B reads =
// conflict-free, unlike r18's AoS-4 which hit 380K conflicts). Chunk chain
// becomes ~3 ds_read_b32 + ballot. mlp gathers xyz from LDS (same bits).
// Producer unchanged (r21 wave-split, relaxed mailbox, PUBK=16).
// ---------------------------------------------------------------------------
__global__ __attribute__((amdgpu_waves_per_eu(1, 1))) __launch_bounds__(256)
void mega_kernel(const float* __restrict__ xyz, const float* __restrict__ points,
                 const float* __restrict__ wt, int* __restrict__ prog,
                 float* __restrict__ cent,
                 float* __restrict__ new_xyz, float* __restrict__ feat)
{
    __shared__ __align__(16) float s4[NPTS * 4];            // producer: AoS4 cloud
                                                            // consumer: SoA x|y|z
    __shared__ __align__(16) unsigned long long sC[2][4];   // fps candidates
    __shared__ int sIdxBuf[4][64];                          // consumer idx handoff

    const int t    = threadIdx.x;
    const int lane = t & 63;
    const int wv   = t >> 6;

    if (blockIdx.x < BATCH) {
        // ================= FPS producer (validated r17 core) =============
#pragma clang fp contract(off)
        const int b = blockIdx.x;
        const float* xb = xyz + (size_t)b * NPTS * 3;
        float* cb = cent + (size_t)b * NPOINT * 4;
        int* pb = prog + b * 32;                            // padded line

        v2f px2[8], py2[8], pz2[8], dist2[8];
#pragma unroll
        for (int j = 0; j < 16; ++j) {
            const int n = j * 256 + t;
            float X = xb[n * 3 + 0];
            float Y = xb[n * 3 + 1];
            float Z = xb[n * 3 + 2];
            s4[n * 4 + 0] = X; s4[n * 4 + 1] = Y; s4[n * 4 + 2] = Z;
            asm volatile("" : "+v"(X), "+v"(Y), "+v"(Z));
            const int p = j >> 1;
            if (j & 1) { px2[p].y = X; py2[p].y = Y; pz2[p].y = Z; dist2[p].y = 1e10f; }
            else       { px2[p].x = X; py2[p].x = Y; pz2[p].x = Z; dist2[p].x = 1e10f; }
        }
        __syncthreads();

        float cx = s4[0], cy = s4[1], cz = s4[2];
        float* out = new_xyz + (size_t)b * NPOINT * 3;

        for (int i = 0; i < NPOINT; ++i) {
            if (t == 0) {            // wave 0: pure output (standalone profile)
                out[i*3+0] = cx; out[i*3+1] = cy; out[i*3+2] = cz;
            }
            if (t == 64) {           // wave 1: mailbox (LLC-direct sc1 stores)
                ull xy = ((ull)__float_as_uint(cy) << 32) |
                         (ull)__float_as_uint(cx);
                __hip_atomic_store((ull*)&cb[i*4], xy, __ATOMIC_RELAXED,
                                   __HIP_MEMORY_SCOPE_AGENT);
                __hip_atomic_store(&cb[i*4+2], cz, __ATOMIC_RELAXED,
                                   __HIP_MEMORY_SCOPE_AGENT);
            }

            v2f c2x; c2x.x = cx; c2x.y = cx;
            v2f c2y; c2y.x = cy; c2y.y = cy;
            v2f c2z; c2z.x = cz; c2z.y = cz;
#pragma unroll
            for (int p = 0; p < 8; ++p) {
                v2f dx = px2[p] - c2x;
                v2f dy = py2[p] - c2y;
                v2f dz = pz2[p] - c2z;
                v2f xx = dx * dx;
                v2f yy = dy * dy;
                v2f zz = dz * dz;
                v2f ss = (xx + yy) + zz;
                dist2[p].x = fminf(dist2[p].x, ss.x);
                dist2[p].y = fminf(dist2[p].y, ss.y);
            }

#define D(j) ((j) & 1 ? dist2[(j) >> 1].y : dist2[(j) >> 1].x)
            float mA = fmaxf(fmaxf(D(0),  D(1)),  D(2));
            float mB = fmaxf(fmaxf(D(3),  D(4)),  D(5));
            float mC = fmaxf(fmaxf(D(6),  D(7)),  D(8));
            float mD = fmaxf(fmaxf(D(9),  D(10)), D(11));
            float mE = fmaxf(fmaxf(D(12), D(13)), D(14));
            float mx = fmaxf(fmaxf(fmaxf(mA, mB), mC),
                             fmaxf(fmaxf(mD, mE), D(15)));
            int bj = 15;
#pragma unroll
            for (int j = 15; j >= 0; --j) bj = (D(j) == mx) ? j : bj;
#undef D
            const int bidx = bj * 256 + t;

            unsigned long long cand =
                ((unsigned long long)__float_as_uint(mx) << 32) |
                (unsigned long long)(unsigned int)~bidx;

#define DPP_RED(CTRL, RMASK)                                                   \
            {                                                                  \
                unsigned int oh = (unsigned int)__builtin_amdgcn_update_dpp(   \
                    0, (int)(unsigned int)(cand >> 32), (CTRL), (RMASK), 0xF, true);\
                unsigned int ol = (unsigned int)__builtin_amdgcn_update_dpp(   \
                    0, (int)(unsigned int)cand, (CTRL), (RMASK), 0xF, true);   \
                unsigned long long o =                                         \
                    ((unsigned long long)oh << 32) | (unsigned long long)ol;   \
                if (o > cand) cand = o;                                        \
            }
            DPP_RED(0x121, 0xF)
            DPP_RED(0x122, 0xF)
            DPP_RED(0x124, 0xF)
            DPP_RED(0x128, 0xF)
            DPP_RED(0x142, 0xA)
            DPP_RED(0x143, 0xC)
#undef DPP_RED

            // batched publication on WAVE 1 (orders wave 1's cent stores)
            if (((i & (PUBK - 1)) == (PUBK - 1)) && t == 64) {
                asm volatile("s_waitcnt vmcnt(0)" ::: "memory");
                __hip_atomic_store(pb, i + 1, __ATOMIC_RELAXED,
                                   __HIP_MEMORY_SCOPE_AGENT);
            }

            const int par = i & 1;
            if (lane == 63) sC[par][wv] = cand;
            asm volatile("s_waitcnt lgkmcnt(0)\n\ts_barrier" ::: "memory");

            const ulonglong2* pc = (const ulonglong2*)&sC[par][0];
            ulonglong2 r0 = pc[0], r1 = pc[1];
            const float4* sx4 = (const float4*)s4;
            float4 f0 = sx4[~(unsigned int)r0.x];
            float4 f1 = sx4[~(unsigned int)r0.y];
            float4 f2 = sx4[~(unsigned int)r1.x];
            float4 f3 = sx4[~(unsigned int)r1.y];
            bool s01 = r0.y > r0.x;
            bool s23 = r1.y > r1.x;
            unsigned long long m01 = s01 ? r0.y : r0.x;
            unsigned long long m23 = s23 ? r1.y : r1.x;
            float4 g01; g01.x = s01 ? f1.x : f0.x; g01.y = s01 ? f1.y : f0.y; g01.z = s01 ? f1.z : f0.z;
            float4 g23; g23.x = s23 ? f3.x : f2.x; g23.y = s23 ? f3.y : f2.y; g23.z = s23 ? f3.z : f2.z;
            bool sF = m23 > m01;
            cx = sF ? g23.x : g01.x;
            cy = sF ? g23.y : g01.y;
            cz = sF ? g23.z : g01.z;
        }
        return;
    }

    // ================= Consumer role: ball + mlp per query-pair =============
    const int cb_ = blockIdx.x - BATCH;         // 0..239
    const int b   = cb_ / NCB;                  // batch
    const int m   = cb_ % NCB;                  // block-in-batch
    const float* xb = xyz + (size_t)b * NPTS * 3;
    const float* cbm = cent + (size_t)b * NPOINT * 4;
    int* pb = prog + b * 32;

    // stage cloud as SoA in LDS: sx = s4[0..], sy = s4[NPTS..], sz = s4[2N..]
    for (int e = t; e < NPTS; e += 256) {
        s4[e]            = xb[e * 3 + 0];
        s4[NPTS + e]     = xb[e * 3 + 1];
        s4[2 * NPTS + e] = xb[e * 3 + 2];
    }
    __syncthreads();
    const float* sx = s4;
    const float* sy = s4 + NPTS;
    const float* sz = s4 + 2 * NPTS;

    const cs_v4f*   Wc1 = (const cs_v4f*)(wt);
    const cs_v4f*   Wc2 = (const cs_v4f*)(wt + 512);
    const cs_v4f*   Wc3 = (const cs_v4f*)(wt + 512 + 4096);
    const cs_float* bi1 = (const cs_float*)(wt + 512 + 4096 + 8192);
    const cs_float* bi2 = bi1 + 64;
    const cs_float* bi3 = bi2 + 64;

    const float r2 = (float)(0.2 * 0.2);
    const int NCH  = NPTS / 64;
    const int widx = m * 4 + wv;                // 0..59 wave slot within batch

    for (int p = widx; p < NPOINT / 2; p += NCB * 4) {
        const int i1 = 2 * p, i2 = 2 * p + 1;

        // deficit-adaptive wait (naps capped small to bound oversleep)
        int pr;
        while ((pr = __hip_atomic_load(pb, __ATOMIC_RELAXED,
                                       __HIP_MEMORY_SCOPE_AGENT)) < i2 + 1) {
            int naps = ((i2 + 1) - pr) >> 4;
            if (naps > 4) naps = 4;
            if (naps == 0) naps = 1;
            for (int s = 0; s < naps; ++s) __builtin_amdgcn_s_sleep(64);
        }

        float cs0[2], cs1[2], cs2[2];
#pragma unroll
        for (int sub = 0; sub < 2; ++sub) {
            const int qi = sub ? i2 : i1;
            ull xy = __hip_atomic_load((const ull*)&cbm[qi*4], __ATOMIC_RELAXED,
                                       __HIP_MEMORY_SCOPE_AGENT);
            cs0[sub] = __uint_as_float((unsigned int)xy);
            cs1[sub] = __uint_as_float((unsigned int)(xy >> 32));
            cs2[sub] = __hip_atomic_load(&cbm[qi*4+2], __ATOMIC_RELAXED,
                                         __HIP_MEMORY_SCOPE_AGENT);
        }

        // ---- ball x2 (EXACT r17 arithmetic; LDS SoA source, same bits) ----
#pragma unroll
        for (int sub = 0; sub < 2; ++sub) {
            const float s0 = cs0[sub], s1 = cs1[sub], s2 = cs2[sub];
            const float ssum = __fadd_rn(__fadd_rn(__fmul_rn(s0,s0), __fmul_rn(s1,s1)),
                                         __fmul_rn(s2,s2));
            int found = 0;
            int first = -1;
            for (int c = 0; c < NCH && found < NSAMPLE; ++c) {
                int n = c * 64 + lane;
                float x = sx[n], y = sy[n], z = sz[n];
                float nsum = __fadd_rn(__fadd_rn(__fmul_rn(x,x), __fmul_rn(y,y)),
                                       __fmul_rn(z,z));
                float dot  = __fmaf_rn(s2, z, __fmaf_rn(s1, y, __fmul_rn(s0, x)));
                float d2   = __fsub_rn(__fadd_rn(ssum, nsum), __fmul_rn(2.0f, dot));
                bool inb = !(d2 > r2);
                unsigned long long mm = __ballot(inb);
                if (first < 0 && mm != 0ull) first = c * 64 + (int)__builtin_ctzll(mm);
                if (inb) {
                    int rank = __popcll(mm & ((1ull << lane) - 1ull));
                    int slot = found + rank;
                    if (slot < NSAMPLE) sIdxBuf[wv][sub * 32 + slot] = n;
                }
                found += __popcll(mm);
            }
            if (found > NSAMPLE) found = NSAMPLE;
            for (int slot = found + lane; slot < NSAMPLE; slot += 64)
                sIdxBuf[wv][sub * 32 + slot] = first;
        }
        asm volatile("s_waitcnt lgkmcnt(0)" ::: "memory");

        // ---- mlp: lanes 0-31 -> i1, lanes 32-63 -> i2 (validated r17) ----
        const int sub = lane >> 5;
        const int k   = lane & 31;
        const int qi  = sub ? i2 : i1;
        const int q   = b * NPOINT + qi;
        const int n   = sIdxBuf[wv][lane];
        const float* pp = points + ((size_t)b * NPTS + n) * 3;

        const float in0 = __fsub_rn(sx[n], cs0[sub]);
        const float in1 = __fsub_rn(sy[n], cs1[sub]);
        const float in2 = __fsub_rn(sz[n], cs2[sub]);
        const float in3 = pp[0], in4 = pp[1], in5 = pp[2];

        v2f x2[32];
#pragma unroll
        for (int d = 0; d < 64; ++d) {
            v4f wa = Wc1[d * 2 + 0];
            v4f wb = Wc1[d * 2 + 1];
            float acc = bi1[d];
            acc = fmaf(in0, wa.x, acc);
            acc = fmaf(in1, wa.y, acc);
            acc = fmaf(in2, wa.z, acc);
            acc = fmaf(in3, wa.w, acc);
            acc = fmaf(in4, wb.x, acc);
            acc = fmaf(in5, wb.y, acc);
            float r = fmaxf(acc, 0.f);
            if (d & 1) x2[d >> 1].y = r; else x2[d >> 1].x = r;
        }

        v2f y2[32];
#pragma unroll
        for (int d = 0; d < 64; ++d) {
            v2f a2; a2.x = 0.f; a2.y = 0.f;
#pragma unroll
            for (int cc = 0; cc < 16; ++cc) {
                v4f w = Wc2[d * 16 + cc];
                v2f wlo; wlo.x = w.x; wlo.y = w.y;
                v2f whi; whi.x = w.z; whi.y = w.w;
                a2 += x2[2*cc]     * wlo;
                a2 += x2[2*cc + 1] * whi;
            }
            float r = fmaxf(bi2[d] + (a2.x + a2.y), 0.f);
            if (d & 1) y2[d >> 1].y = r; else y2[d >> 1].x = r;
        }

#define POOL_MAX(vv)                                                           \
        {                                                                      \
            float o_;                                                          \
            o_ = __int_as_float(__builtin_amdgcn_update_dpp(                   \
                0, __float_as_int(vv), 0x121, 0xF, 0xF, true));                \
            vv = fmaxf(vv, o_);                                                \
            o_ = __int_as_float(__builtin_amdgcn_update_dpp(                   \
                0, __float_as_int(vv), 0x122, 0xF, 0xF, true));                \
            vv = fmaxf(vv, o_);                                                \
            o_ = __int_as_float(__builtin_amdgcn_update_dpp(                   \
                0, __float_as_int(vv), 0x124, 0xF, 0xF, true));                \
            vv = fmaxf(vv, o_);                                                \
            o_ = __int_as_float(__builtin_amdgcn_update_dpp(                   \
                0, __float_as_int(vv), 0x128, 0xF, 0xF, true));                \
            vv = fmaxf(vv, o_);                                                \
            vv = fmaxf(vv, __shfl_xor(vv, 16));                                \
        }

        float* fq = feat + (size_t)q * 128;
#pragma unroll
        for (int d = 0; d < 128; ++d) {
            v2f a2; a2.x = 0.f; a2.y = 0.f;
#pragma unroll
            for (int cc = 0; cc < 16; ++cc) {
                v4f w = Wc3[d * 16 + cc];
                v2f wlo; wlo.x = w.x; wlo.y = w.y;
                v2f whi; whi.x = w.z; whi.y = w.w;
                a2 += y2[2*cc]     * wlo;
                a2 += y2[2*cc + 1] * whi;
            }
            float vv = fmaxf(bi3[d] + (a2.x + a2.y), 0.f);
            POOL_MAX(vv)
            if (k == 0) fq[d] = vv;
        }
#undef POOL_MAX
    }
}

extern "C" void kernel_launch(void* const* d_in, const int* in_sizes, int n_in,
                              void* d_out, int out_size, void* d_ws, size_t ws_size,
                              hipStream_t stream)
{
    (void)in_sizes; (void)n_in; (void)out_size; (void)ws_size;

    const float* xyz    = (const float*)d_in[0];
    const float* points = (const float*)d_in[1];
    const float* W1 = (const float*)d_in[2];
    const float* g1 = (const float*)d_in[3];
    const float* b1 = (const float*)d_in[4];
    const float* m1 = (const float*)d_in[5];
    const float* v1 = (const float*)d_in[6];
    const float* W2 = (const float*)d_in[7];
    const float* g2 = (const float*)d_in[8];
    const float* b2 = (const float*)d_in[9];
    const float* m2 = (const float*)d_in[10];
    const float* v2 = (const float*)d_in[11];
    const float* W3 = (const float*)d_in[12];
    const float* g3 = (const float*)d_in[13];
    const float* b3 = (const float*)d_in[14];
    const float* m3 = (const float*)d_in[15];
    const float* v3 = (const float*)d_in[16];

    float* out_f    = (float*)d_out;
    float* new_xyz  = out_f;                                  // B*NPOINT*3
    float* feat     = out_f + (size_t)BATCH * NPOINT * 3;     // B*NPOINT*128

    // ws layout: [0,4KB) prog (128B/batch) | [4KB,260KB) cent | [2MB,..) wt
    int*   prog = (int*)d_ws;
    float* cent = (float*)((char*)d_ws + 4 * 1024);
    float* wt   = (float*)((char*)d_ws + 2 * 1024 * 1024);

    hipMemsetAsync(prog, 0, BATCH * 32 * sizeof(int), stream);
    prep_kernel<<<1, 256, 0, stream>>>(W1, g1, b1, m1, v1,
                                       W2, g2, b2, m2, v2,
                                       W3, g3, b3, m3, v3, wt);
    mega_kernel<<<BATCH + BATCH * NCB, 256, 0, stream>>>(xyz, points, wt, prog,
                                                         cent, new_xyz, feat);
}